// Round 1
// baseline (3310.720 us; speedup 1.0000x reference)
//
#include <hip/hip_runtime.h>

#define NNODES 100000
#define NEDGES 1600000
#define DFEAT  128
#define NPOOL  25000

// ---------------- kernels ----------------

__global__ void copy_x_kernel(const float* __restrict__ x, float* __restrict__ x1, int n4) {
    int i = blockIdx.x * blockDim.x + threadIdx.x;
    int stride = gridDim.x * blockDim.x;
    for (; i < n4; i += stride) {
        ((float4*)x1)[i] = ((const float4*)x)[i];
    }
}

__global__ void set_inv_kernel(const int* __restrict__ sel, int* __restrict__ inv) {
    int i = blockIdx.x * blockDim.x + threadIdx.x;
    if (i < NPOOL) inv[sel[i]] = i;
}

// hop 1: x1[dst] += x[src] * w   (x1 pre-initialized to x for the residual)
// 32 threads per edge, each handling 4 consecutive floats (float4 gather).
__global__ void scatter1_kernel(const float* __restrict__ x,
                                const float* __restrict__ w,
                                const int* __restrict__ src,
                                const int* __restrict__ dst,
                                float* __restrict__ x1) {
    int gid = blockIdx.x * blockDim.x + threadIdx.x;
    int e = gid >> 5;
    if (e >= NEDGES) return;
    int j = gid & 31;
    float we = w[e];
    int s = src[e];
    int t = dst[e];
    float4 v = ((const float4*)(x + (size_t)s * DFEAT))[j];
    float* p = x1 + (size_t)t * DFEAT + j * 4;
    atomicAdd(p + 0, v.x * we);
    atomicAdd(p + 1, v.y * we);
    atomicAdd(p + 2, v.z * we);
    atomicAdd(p + 3, v.w * we);
}

// hop 2: agg2[inv[dst]] += x1[src] * w, only for selected dst
__global__ void scatter2_kernel(const float* __restrict__ x1,
                                const float* __restrict__ w,
                                const int* __restrict__ src,
                                const int* __restrict__ dst,
                                const int* __restrict__ inv,
                                float* __restrict__ agg2) {
    int gid = blockIdx.x * blockDim.x + threadIdx.x;
    int e = gid >> 5;
    if (e >= NEDGES) return;
    int t = dst[e];
    int slot = inv[t];
    if (slot < 0) return;
    int j = gid & 31;
    float we = w[e];
    int s = src[e];
    float4 v = ((const float4*)(x1 + (size_t)s * DFEAT))[j];
    float* p = agg2 + (size_t)slot * DFEAT + j * 4;
    atomicAdd(p + 0, v.x * we);
    atomicAdd(p + 1, v.y * we);
    atomicAdd(p + 2, v.z * we);
    atomicAdd(p + 3, v.w * we);
}

// out[i] = x1[sel[i]] + agg2[inv[sel[i]]]
__global__ void finalize_kernel(const float* __restrict__ x1,
                                const float* __restrict__ agg2,
                                const int* __restrict__ sel,
                                const int* __restrict__ inv,
                                float* __restrict__ out) {
    int i = blockIdx.x * blockDim.x + threadIdx.x;  // over NPOOL*32 float4s
    if (i >= NPOOL * 32) return;
    int row = i >> 5;
    int j = i & 31;
    int node = sel[row];
    int slot = inv[node];  // always >= 0 for selected nodes
    float4 a = ((const float4*)(x1 + (size_t)node * DFEAT))[j];
    float4 b = ((const float4*)(agg2 + (size_t)slot * DFEAT))[j];
    float4 o;
    o.x = a.x + b.x;
    o.y = a.y + b.y;
    o.z = a.z + b.z;
    o.w = a.w + b.w;
    ((float4*)out)[i] = o;
}

// ---------------- launch ----------------

extern "C" void kernel_launch(void* const* d_in, const int* in_sizes, int n_in,
                              void* d_out, int out_size, void* d_ws, size_t ws_size,
                              hipStream_t stream) {
    const float* x         = (const float*)d_in[0];            // [NNODES, DFEAT]
    const float* edge_attr = (const float*)d_in[1];            // [NEDGES]
    const int*   edge_idx  = (const int*)d_in[2];              // [2, NEDGES]
    const int*   sel       = (const int*)d_in[3];              // [NPOOL]
    const int*   src = edge_idx;
    const int*   dst = edge_idx + NEDGES;
    float* out = (float*)d_out;

    // workspace layout
    char* ws = (char*)d_ws;
    float* x1   = (float*)ws;                                  // NNODES*DFEAT f32 = 51.2 MB
    ws += (size_t)NNODES * DFEAT * sizeof(float);
    float* agg2 = (float*)ws;                                  // NPOOL*DFEAT f32 = 12.8 MB
    ws += (size_t)NPOOL * DFEAT * sizeof(float);
    int* inv    = (int*)ws;                                    // NNODES int = 0.4 MB

    // init: inv = -1, agg2 = 0
    hipMemsetAsync(inv, 0xFF, (size_t)NNODES * sizeof(int), stream);
    hipMemsetAsync(agg2, 0, (size_t)NPOOL * DFEAT * sizeof(float), stream);

    // x1 = x (residual)
    {
        int n4 = NNODES * DFEAT / 4;
        copy_x_kernel<<<2048, 256, 0, stream>>>(x, x1, n4);
    }
    // inv[sel[i]] = i
    set_inv_kernel<<<(NPOOL + 255) / 256, 256, 0, stream>>>(sel, inv);

    // hop 1 scatter
    {
        long long threads = (long long)NEDGES * 32;
        int blocks = (int)((threads + 255) / 256);
        scatter1_kernel<<<blocks, 256, 0, stream>>>(x, edge_attr, src, dst, x1);
    }
    // hop 2 scatter (selected dst only)
    {
        long long threads = (long long)NEDGES * 32;
        int blocks = (int)((threads + 255) / 256);
        scatter2_kernel<<<blocks, 256, 0, stream>>>(x1, edge_attr, src, dst, inv, agg2);
    }
    // gather output
    {
        int threads = NPOOL * 32;
        finalize_kernel<<<(threads + 255) / 256, 256, 0, stream>>>(x1, agg2, sel, inv, out);
    }
}

// Round 2
// 748.522 us; speedup vs baseline: 4.4230x; 4.4230x over previous
//
#include <hip/hip_runtime.h>

#define NNODES 100000
#define NEDGES 1600000
#define DFEAT  128
#define NPOOL  25000

// ---------------- CSR build ----------------

__global__ void hist_kernel(const int* __restrict__ dst, int* __restrict__ deg) {
    int e = blockIdx.x * blockDim.x + threadIdx.x;
    if (e >= NEDGES) return;
    atomicAdd(&deg[dst[e]], 1);
}

// single-block exclusive scan of deg[NNODES] -> rowptr, cursor
__global__ void scan_kernel(const int* __restrict__ deg,
                            int* __restrict__ rowptr,
                            int* __restrict__ cursor) {
    __shared__ int lds[1024];
    int t = threadIdx.x;
    const int chunk = (NNODES + 1023) / 1024;  // 98
    int lo = t * chunk;
    int hi = lo + chunk; if (hi > NNODES) hi = NNODES;
    if (lo > NNODES) lo = NNODES;
    int sum = 0;
    for (int i = lo; i < hi; ++i) sum += deg[i];
    lds[t] = sum;
    __syncthreads();
    // Hillis-Steele inclusive scan
    for (int off = 1; off < 1024; off <<= 1) {
        int v = (t >= off) ? lds[t - off] : 0;
        __syncthreads();
        lds[t] += v;
        __syncthreads();
    }
    int run = (t == 0) ? 0 : lds[t - 1];
    for (int i = lo; i < hi; ++i) {
        rowptr[i] = run;
        cursor[i] = run;
        run += deg[i];
    }
    if (t == 1023) rowptr[NNODES] = run;
}

__global__ void build_kernel(const int* __restrict__ dst,
                             int* __restrict__ cursor,
                             int* __restrict__ csr_eid) {
    int e = blockIdx.x * blockDim.x + threadIdx.x;
    if (e >= NEDGES) return;
    int t = dst[e];
    int pos = atomicAdd(&cursor[t], 1);
    csr_eid[pos] = e;
}

// ---------------- aggregation ----------------

// hop 1: one 64-lane wave per node; x1[n] = x[n] + sum_{e: dst=n} x[src[e]] * w[e]
__global__ void agg1_kernel(const float* __restrict__ x,
                            const float* __restrict__ w,
                            const int* __restrict__ srcarr,
                            const int* __restrict__ rowptr,
                            const int* __restrict__ csr_eid,
                            float* __restrict__ x1) {
    int gid = blockIdx.x * blockDim.x + threadIdx.x;
    int node = gid >> 6;
    if (node >= NNODES) return;
    int lane = threadIdx.x & 63;
    int beg = rowptr[node];
    int end = rowptr[node + 1];
    const float2* xf2 = (const float2*)x;
    float2 acc = make_float2(0.f, 0.f);
    for (int i = beg; i < end; ++i) {
        int eid = csr_eid[i];
        int s = srcarr[eid];
        float we = w[eid];
        float2 v = xf2[(size_t)s * 64 + lane];
        acc.x += v.x * we;
        acc.y += v.y * we;
    }
    float2 base = xf2[(size_t)node * 64 + lane];
    float2 o = make_float2(base.x + acc.x, base.y + acc.y);
    ((float2*)x1)[(size_t)node * 64 + lane] = o;
}

// hop 2: one wave per pooled row; out[i] = x1[sel[i]] + sum_{e: dst=sel[i]} x1[src[e]] * w[e]
__global__ void agg2_kernel(const float* __restrict__ x1,
                            const float* __restrict__ w,
                            const int* __restrict__ srcarr,
                            const int* __restrict__ rowptr,
                            const int* __restrict__ csr_eid,
                            const int* __restrict__ sel,
                            float* __restrict__ out) {
    int gid = blockIdx.x * blockDim.x + threadIdx.x;
    int row = gid >> 6;
    if (row >= NPOOL) return;
    int lane = threadIdx.x & 63;
    int node = sel[row];
    int beg = rowptr[node];
    int end = rowptr[node + 1];
    const float2* xf2 = (const float2*)x1;
    float2 acc = make_float2(0.f, 0.f);
    for (int i = beg; i < end; ++i) {
        int eid = csr_eid[i];
        int s = srcarr[eid];
        float we = w[eid];
        float2 v = xf2[(size_t)s * 64 + lane];
        acc.x += v.x * we;
        acc.y += v.y * we;
    }
    float2 base = xf2[(size_t)node * 64 + lane];
    float2 o = make_float2(base.x + acc.x, base.y + acc.y);
    ((float2*)out)[(size_t)row * 64 + lane] = o;
}

// ---------------- launch ----------------

extern "C" void kernel_launch(void* const* d_in, const int* in_sizes, int n_in,
                              void* d_out, int out_size, void* d_ws, size_t ws_size,
                              hipStream_t stream) {
    const float* x         = (const float*)d_in[0];            // [NNODES, DFEAT]
    const float* edge_attr = (const float*)d_in[1];            // [NEDGES]
    const int*   edge_idx  = (const int*)d_in[2];              // [2, NEDGES]
    const int*   sel       = (const int*)d_in[3];              // [NPOOL]
    const int*   src = edge_idx;
    const int*   dst = edge_idx + NEDGES;
    float* out = (float*)d_out;

    // workspace layout (58.4 MB total)
    char* ws = (char*)d_ws;
    float* x1     = (float*)ws;  ws += (size_t)NNODES * DFEAT * sizeof(float);  // 51.2 MB
    int*   rowptr = (int*)ws;    ws += (size_t)(NNODES + 1) * sizeof(int);
    int*   cursor = (int*)ws;    ws += (size_t)NNODES * sizeof(int);
    int*   csr_eid= (int*)ws;    ws += (size_t)NEDGES * sizeof(int);            // 6.4 MB
    int*   deg    = cursor;      // reuse cursor for histogram (scan overwrites with rowptr vals)

    // deg = 0
    hipMemsetAsync(deg, 0, (size_t)NNODES * sizeof(int), stream);

    // 1) histogram of dst
    hist_kernel<<<(NEDGES + 255) / 256, 256, 0, stream>>>(dst, deg);
    // 2) exclusive scan -> rowptr, cursor  (deg aliases cursor: scan reads deg[i]
    //    before writing cursor[i] in the same loop iteration, so aliasing is safe)
    scan_kernel<<<1, 1024, 0, stream>>>(deg, rowptr, cursor);
    // 3) bucket scatter edge ids
    build_kernel<<<(NEDGES + 255) / 256, 256, 0, stream>>>(dst, cursor, csr_eid);

    // 4) hop 1 (all nodes)
    {
        long long threads = (long long)NNODES * 64;
        int blocks = (int)((threads + 255) / 256);
        agg1_kernel<<<blocks, 256, 0, stream>>>(x, edge_attr, src, rowptr, csr_eid, x1);
    }
    // 5) hop 2 (selected rows only), fused with output gather
    {
        long long threads = (long long)NPOOL * 64;
        int blocks = (int)((threads + 255) / 256);
        agg2_kernel<<<blocks, 256, 0, stream>>>(x1, edge_attr, src, rowptr, csr_eid, sel, out);
    }
}

// Round 3
// 486.780 us; speedup vs baseline: 6.8013x; 1.5377x over previous
//
#include <hip/hip_runtime.h>

#define NNODES 100000
#define NEDGES 1600000
#define DFEAT  128
#define NPOOL  25000

// ---------------- CSR build ----------------

// histogram of dst into rowptr (pre-zeroed)
__global__ void hist_kernel(const int* __restrict__ dst, int* __restrict__ rowptr) {
    int e = blockIdx.x * blockDim.x + threadIdx.x;
    if (e >= NEDGES) return;
    atomicAdd(&rowptr[dst[e]], 1);
}

// single-block in-place exclusive scan: rowptr[i] (counts) -> start offsets
__global__ void scan_kernel(int* __restrict__ rowptr) {
    __shared__ int lds[1024];
    int t = threadIdx.x;
    const int chunk = (NNODES + 1023) / 1024;  // 98
    int lo = t * chunk;
    int hi = lo + chunk; if (hi > NNODES) hi = NNODES;
    if (lo > NNODES) lo = NNODES;
    int sum = 0;
    for (int i = lo; i < hi; ++i) sum += rowptr[i];
    lds[t] = sum;
    __syncthreads();
    // Hillis-Steele inclusive scan over block sums
    for (int off = 1; off < 1024; off <<= 1) {
        int v = (t >= off) ? lds[t - off] : 0;
        __syncthreads();
        lds[t] += v;
        __syncthreads();
    }
    int run = (t == 0) ? 0 : lds[t - 1];
    for (int i = lo; i < hi; ++i) {
        int dv = rowptr[i];       // read BEFORE overwrite (in-place)
        rowptr[i] = run;
        run += dv;
    }
}

// scatter {src, w} into CSR order; rowptr[t] becomes END pointer of row t
__global__ void build_kernel(const int* __restrict__ dst,
                             const int* __restrict__ src,
                             const float* __restrict__ w,
                             int* __restrict__ rowptr,
                             int2* __restrict__ csr_sw) {
    int e = blockIdx.x * blockDim.x + threadIdx.x;
    if (e >= NEDGES) return;
    int t = dst[e];
    int pos = atomicAdd(&rowptr[t], 1);
    csr_sw[pos] = make_int2(src[e], __float_as_int(w[e]));
}

// ---------------- aggregation ----------------
// After build: row t spans [ t ? rowptr[t-1] : 0 , rowptr[t] ).

// one 64-lane wave per node; out_row = x[node] + sum_e x[src_e] * w_e
__device__ __forceinline__ void agg_row(const float2* __restrict__ xf2,
                                        const int2* __restrict__ csr_sw,
                                        int beg, int end, int node, int lane,
                                        float2& acc) {
    for (int base = beg; base < end; base += 64) {
        int cnt = end - base; if (cnt > 64) cnt = 64;
        int2 sw = make_int2(0, 0);
        if (lane < cnt) sw = csr_sw[base + lane];
        int   my_s = sw.x;
        float my_w = __int_as_float(sw.y);
        int d = 0;
        for (; d + 4 <= cnt; d += 4) {
            int   s0 = __shfl(my_s, d + 0); float w0 = __shfl(my_w, d + 0);
            int   s1 = __shfl(my_s, d + 1); float w1 = __shfl(my_w, d + 1);
            int   s2 = __shfl(my_s, d + 2); float w2 = __shfl(my_w, d + 2);
            int   s3 = __shfl(my_s, d + 3); float w3 = __shfl(my_w, d + 3);
            float2 v0 = xf2[(size_t)s0 * 64 + lane];
            float2 v1 = xf2[(size_t)s1 * 64 + lane];
            float2 v2 = xf2[(size_t)s2 * 64 + lane];
            float2 v3 = xf2[(size_t)s3 * 64 + lane];
            acc.x += v0.x * w0; acc.y += v0.y * w0;
            acc.x += v1.x * w1; acc.y += v1.y * w1;
            acc.x += v2.x * w2; acc.y += v2.y * w2;
            acc.x += v3.x * w3; acc.y += v3.y * w3;
        }
        for (; d < cnt; ++d) {
            int   s = __shfl(my_s, d);
            float wv = __shfl(my_w, d);
            float2 v = xf2[(size_t)s * 64 + lane];
            acc.x += v.x * wv; acc.y += v.y * wv;
        }
    }
}

__global__ __launch_bounds__(256) void agg1_kernel(const float* __restrict__ x,
                                                   const int2* __restrict__ csr_sw,
                                                   const int* __restrict__ rowptr,
                                                   float* __restrict__ x1) {
    int gid = blockIdx.x * blockDim.x + threadIdx.x;
    int node = gid >> 6;
    if (node >= NNODES) return;
    int lane = threadIdx.x & 63;
    int beg = node ? rowptr[node - 1] : 0;
    int end = rowptr[node];
    const float2* xf2 = (const float2*)x;
    float2 acc = xf2[(size_t)node * 64 + lane];  // residual (overlaps segment load)
    agg_row(xf2, csr_sw, beg, end, node, lane, acc);
    ((float2*)x1)[(size_t)node * 64 + lane] = acc;
}

__global__ __launch_bounds__(256) void agg2_kernel(const float* __restrict__ x1,
                                                   const int2* __restrict__ csr_sw,
                                                   const int* __restrict__ rowptr,
                                                   const int* __restrict__ sel,
                                                   float* __restrict__ out) {
    int gid = blockIdx.x * blockDim.x + threadIdx.x;
    int row = gid >> 6;
    if (row >= NPOOL) return;
    int lane = threadIdx.x & 63;
    int node = sel[row];
    int beg = node ? rowptr[node - 1] : 0;
    int end = rowptr[node];
    const float2* xf2 = (const float2*)x1;
    float2 acc = xf2[(size_t)node * 64 + lane];  // residual
    agg_row(xf2, csr_sw, beg, end, node, lane, acc);
    ((float2*)out)[(size_t)row * 64 + lane] = acc;
}

// ---------------- launch ----------------

extern "C" void kernel_launch(void* const* d_in, const int* in_sizes, int n_in,
                              void* d_out, int out_size, void* d_ws, size_t ws_size,
                              hipStream_t stream) {
    const float* x         = (const float*)d_in[0];            // [NNODES, DFEAT]
    const float* edge_attr = (const float*)d_in[1];            // [NEDGES]
    const int*   edge_idx  = (const int*)d_in[2];              // [2, NEDGES]
    const int*   sel       = (const int*)d_in[3];              // [NPOOL]
    const int*   src = edge_idx;
    const int*   dst = edge_idx + NEDGES;
    float* out = (float*)d_out;

    // workspace layout: 51.2 + 0.4 + 12.8 = 64.4 MB (== proven round-1 budget)
    char* ws = (char*)d_ws;
    float* x1     = (float*)ws;  ws += (size_t)NNODES * DFEAT * sizeof(float);  // 51.2 MB
    int*   rowptr = (int*)ws;    ws += (size_t)NNODES * sizeof(int);            // 0.4 MB
    int2*  csr_sw = (int2*)ws;   ws += (size_t)NEDGES * sizeof(int2);           // 12.8 MB

    // rowptr = 0 (serves as histogram, then scan in-place, then end-pointers)
    hipMemsetAsync(rowptr, 0, (size_t)NNODES * sizeof(int), stream);

    // 1) histogram of dst
    hist_kernel<<<(NEDGES + 255) / 256, 256, 0, stream>>>(dst, rowptr);
    // 2) in-place exclusive scan -> start offsets
    scan_kernel<<<1, 1024, 0, stream>>>(rowptr);
    // 3) bucket scatter {src,w}; rowptr becomes end-pointers
    build_kernel<<<(NEDGES + 255) / 256, 256, 0, stream>>>(dst, src, edge_attr, rowptr, csr_sw);

    // 4) hop 1 (all nodes)
    {
        long long threads = (long long)NNODES * 64;
        int blocks = (int)((threads + 255) / 256);
        agg1_kernel<<<blocks, 256, 0, stream>>>(x, csr_sw, rowptr, x1);
    }
    // 5) hop 2 (selected rows only), fused with residual + output gather
    {
        long long threads = (long long)NPOOL * 64;
        int blocks = (int)((threads + 255) / 256);
        agg2_kernel<<<blocks, 256, 0, stream>>>(x1, csr_sw, rowptr, sel, out);
    }
}

// Round 4
// 341.897 us; speedup vs baseline: 9.6834x; 1.4238x over previous
//
#include <hip/hip_runtime.h>

#define NNODES 100000
#define NEDGES 1600000
#define DFEAT  128
#define NPOOL  25000

#define SCAN_CHUNK 1024                              // elements per scan block
#define SCAN_BLOCKS ((NNODES + SCAN_CHUNK - 1) / SCAN_CHUNK)   // 98

// ---------------- CSR build ----------------

// histogram of dst into rowptr (pre-zeroed)
__global__ void hist_kernel(const int* __restrict__ dst, int* __restrict__ rowptr) {
    int e = blockIdx.x * blockDim.x + threadIdx.x;
    if (e >= NEDGES) return;
    atomicAdd(&rowptr[dst[e]], 1);
}

// scan phase 1: per-block sums of rowptr -> partials
__global__ __launch_bounds__(256) void scan1_kernel(const int* __restrict__ rowptr,
                                                    int* __restrict__ partials) {
    __shared__ int lds[256];
    int t = threadIdx.x;
    int base = blockIdx.x * SCAN_CHUNK + t * 4;
    int sum = 0;
    #pragma unroll
    for (int k = 0; k < 4; ++k) {
        int i = base + k;
        if (i < NNODES) sum += rowptr[i];
    }
    lds[t] = sum;
    __syncthreads();
    for (int off = 128; off > 0; off >>= 1) {
        if (t < off) lds[t] += lds[t + off];
        __syncthreads();
    }
    if (t == 0) partials[blockIdx.x] = lds[0];
}

// scan phase 2: exclusive scan of partials (tiny, one block)
__global__ void scan2_kernel(int* __restrict__ partials) {
    __shared__ int lds[128];
    int t = threadIdx.x;
    int v = (t < SCAN_BLOCKS) ? partials[t] : 0;
    lds[t] = v;
    __syncthreads();
    for (int off = 1; off < 128; off <<= 1) {
        int u = (t >= off) ? lds[t - off] : 0;
        __syncthreads();
        lds[t] += u;
        __syncthreads();
    }
    if (t < SCAN_BLOCKS) partials[t] = lds[t] - v;   // exclusive
}

// scan phase 3: in-place exclusive scan of rowptr using partial offsets
__global__ __launch_bounds__(256) void scan3_kernel(int* __restrict__ rowptr,
                                                    const int* __restrict__ partials) {
    __shared__ int lds[256];
    int t = threadIdx.x;
    int base = blockIdx.x * SCAN_CHUNK + t * 4;
    int v[4];
    int sum = 0;
    #pragma unroll
    for (int k = 0; k < 4; ++k) {
        int i = base + k;
        v[k] = (i < NNODES) ? rowptr[i] : 0;
        sum += v[k];
    }
    lds[t] = sum;
    __syncthreads();
    for (int off = 1; off < 256; off <<= 1) {
        int u = (t >= off) ? lds[t - off] : 0;
        __syncthreads();
        lds[t] += u;
        __syncthreads();
    }
    int run = partials[blockIdx.x] + lds[t] - sum;   // exclusive prefix for this thread
    #pragma unroll
    for (int k = 0; k < 4; ++k) {
        int i = base + k;
        if (i < NNODES) rowptr[i] = run;
        run += v[k];
    }
}

// scatter {src, w} into CSR order; rowptr[t] becomes END pointer of row t
__global__ void build_kernel(const int* __restrict__ dst,
                             const int* __restrict__ src,
                             const float* __restrict__ w,
                             int* __restrict__ rowptr,
                             int2* __restrict__ csr_sw) {
    int e = blockIdx.x * blockDim.x + threadIdx.x;
    if (e >= NEDGES) return;
    int t = dst[e];
    int pos = atomicAdd(&rowptr[t], 1);
    csr_sw[pos] = make_int2(src[e], __float_as_int(w[e]));
}

// ---------------- aggregation ----------------
// After build: row t spans [ t ? rowptr[t-1] : 0 , rowptr[t] ).

// one 64-lane wave per node; acc += sum_e x[src_e] * w_e
__device__ __forceinline__ void agg_row(const float2* __restrict__ xf2,
                                        const int2* __restrict__ csr_sw,
                                        int beg, int end, int lane,
                                        float2& acc) {
    for (int base = beg; base < end; base += 64) {
        int cnt = end - base; if (cnt > 64) cnt = 64;
        int2 sw = make_int2(0, 0);
        if (lane < cnt) sw = csr_sw[base + lane];
        int   my_s = sw.x;
        float my_w = __int_as_float(sw.y);
        int d = 0;
        for (; d + 4 <= cnt; d += 4) {
            int   s0 = __shfl(my_s, d + 0); float w0 = __shfl(my_w, d + 0);
            int   s1 = __shfl(my_s, d + 1); float w1 = __shfl(my_w, d + 1);
            int   s2 = __shfl(my_s, d + 2); float w2 = __shfl(my_w, d + 2);
            int   s3 = __shfl(my_s, d + 3); float w3 = __shfl(my_w, d + 3);
            float2 v0 = xf2[(size_t)s0 * 64 + lane];
            float2 v1 = xf2[(size_t)s1 * 64 + lane];
            float2 v2 = xf2[(size_t)s2 * 64 + lane];
            float2 v3 = xf2[(size_t)s3 * 64 + lane];
            acc.x += v0.x * w0; acc.y += v0.y * w0;
            acc.x += v1.x * w1; acc.y += v1.y * w1;
            acc.x += v2.x * w2; acc.y += v2.y * w2;
            acc.x += v3.x * w3; acc.y += v3.y * w3;
        }
        for (; d < cnt; ++d) {
            int   s = __shfl(my_s, d);
            float wv = __shfl(my_w, d);
            float2 v = xf2[(size_t)s * 64 + lane];
            acc.x += v.x * wv; acc.y += v.y * wv;
        }
    }
}

__global__ __launch_bounds__(256) void agg1_kernel(const float* __restrict__ x,
                                                   const int2* __restrict__ csr_sw,
                                                   const int* __restrict__ rowptr,
                                                   float* __restrict__ x1) {
    int gid = blockIdx.x * blockDim.x + threadIdx.x;
    int node = gid >> 6;
    if (node >= NNODES) return;
    int lane = threadIdx.x & 63;
    int beg = node ? rowptr[node - 1] : 0;
    int end = rowptr[node];
    const float2* xf2 = (const float2*)x;
    float2 acc = xf2[(size_t)node * 64 + lane];  // residual (overlaps segment load)
    agg_row(xf2, csr_sw, beg, end, lane, acc);
    ((float2*)x1)[(size_t)node * 64 + lane] = acc;
}

__global__ __launch_bounds__(256) void agg2_kernel(const float* __restrict__ x1,
                                                   const int2* __restrict__ csr_sw,
                                                   const int* __restrict__ rowptr,
                                                   const int* __restrict__ sel,
                                                   float* __restrict__ out) {
    int gid = blockIdx.x * blockDim.x + threadIdx.x;
    int row = gid >> 6;
    if (row >= NPOOL) return;
    int lane = threadIdx.x & 63;
    int node = sel[row];
    int beg = node ? rowptr[node - 1] : 0;
    int end = rowptr[node];
    const float2* xf2 = (const float2*)x1;
    float2 acc = xf2[(size_t)node * 64 + lane];  // residual
    agg_row(xf2, csr_sw, beg, end, lane, acc);
    ((float2*)out)[(size_t)row * 64 + lane] = acc;
}

// ---------------- launch ----------------

extern "C" void kernel_launch(void* const* d_in, const int* in_sizes, int n_in,
                              void* d_out, int out_size, void* d_ws, size_t ws_size,
                              hipStream_t stream) {
    const float* x         = (const float*)d_in[0];            // [NNODES, DFEAT]
    const float* edge_attr = (const float*)d_in[1];            // [NEDGES]
    const int*   edge_idx  = (const int*)d_in[2];              // [2, NEDGES]
    const int*   sel       = (const int*)d_in[3];              // [NPOOL]
    const int*   src = edge_idx;
    const int*   dst = edge_idx + NEDGES;
    float* out = (float*)d_out;

    // workspace layout: 51.2 + 0.4 + 12.8 + tiny = ~64.4 MB
    char* ws = (char*)d_ws;
    float* x1       = (float*)ws;  ws += (size_t)NNODES * DFEAT * sizeof(float);  // 51.2 MB
    int*   rowptr   = (int*)ws;    ws += (size_t)NNODES * sizeof(int);            // 0.4 MB
    int2*  csr_sw   = (int2*)ws;   ws += (size_t)NEDGES * sizeof(int2);           // 12.8 MB
    int*   partials = (int*)ws;    ws += (size_t)SCAN_BLOCKS * sizeof(int);

    // rowptr = 0 (histogram -> scan in-place -> end-pointers after build)
    hipMemsetAsync(rowptr, 0, (size_t)NNODES * sizeof(int), stream);

    // 1) histogram of dst
    hist_kernel<<<(NEDGES + 255) / 256, 256, 0, stream>>>(dst, rowptr);
    // 2) hierarchical exclusive scan (in-place on rowptr)
    scan1_kernel<<<SCAN_BLOCKS, 256, 0, stream>>>(rowptr, partials);
    scan2_kernel<<<1, 128, 0, stream>>>(partials);
    scan3_kernel<<<SCAN_BLOCKS, 256, 0, stream>>>(rowptr, partials);
    // 3) bucket scatter {src,w}; rowptr becomes end-pointers
    build_kernel<<<(NEDGES + 255) / 256, 256, 0, stream>>>(dst, src, edge_attr, rowptr, csr_sw);

    // 4) hop 1 (all nodes)
    {
        long long threads = (long long)NNODES * 64;
        int blocks = (int)((threads + 255) / 256);
        agg1_kernel<<<blocks, 256, 0, stream>>>(x, csr_sw, rowptr, x1);
    }
    // 5) hop 2 (selected rows only), fused with residual + output gather
    {
        long long threads = (long long)NPOOL * 64;
        int blocks = (int)((threads + 255) / 256);
        agg2_kernel<<<blocks, 256, 0, stream>>>(x1, csr_sw, rowptr, sel, out);
    }
}

// Round 5
// 304.179 us; speedup vs baseline: 10.8841x; 1.1240x over previous
//
#include <hip/hip_runtime.h>

#define NNODES 100000
#define NEDGES 1600000
#define DFEAT  128
#define NPOOL  25000

#define SCAN_CHUNK 1024                              // elements per scan block
#define SCAN_BLOCKS ((NNODES + SCAN_CHUNK - 1) / SCAN_CHUNK)   // 98

#define NRANGE 8                                     // dst-range groups (== XCDs)
#define RSPAN ((NNODES + NRANGE - 1) / NRANGE)       // 12500 nodes per range
#define BUILD_BLOCKS 2048
#define GSTRIDE ((BUILD_BLOCKS / NRANGE) * 256)      // threads per range group

// ---------------- CSR build ----------------

// histogram of dst into rowptr (pre-zeroed), 4 edges/thread for MLP
__global__ __launch_bounds__(256) void hist_kernel(const int* __restrict__ dst,
                                                   int* __restrict__ rowptr) {
    int i = blockIdx.x * blockDim.x + threadIdx.x;   // over NEDGES/4 int4s
    const int n4 = NEDGES / 4;
    if (i >= n4) return;
    int4 d4 = ((const int4*)dst)[i];
    atomicAdd(&rowptr[d4.x], 1);
    atomicAdd(&rowptr[d4.y], 1);
    atomicAdd(&rowptr[d4.z], 1);
    atomicAdd(&rowptr[d4.w], 1);
}

// scan phase 1: per-block sums of rowptr -> partials
__global__ __launch_bounds__(256) void scan1_kernel(const int* __restrict__ rowptr,
                                                    int* __restrict__ partials) {
    __shared__ int lds[256];
    int t = threadIdx.x;
    int base = blockIdx.x * SCAN_CHUNK + t * 4;
    int sum = 0;
    #pragma unroll
    for (int k = 0; k < 4; ++k) {
        int i = base + k;
        if (i < NNODES) sum += rowptr[i];
    }
    lds[t] = sum;
    __syncthreads();
    for (int off = 128; off > 0; off >>= 1) {
        if (t < off) lds[t] += lds[t + off];
        __syncthreads();
    }
    if (t == 0) partials[blockIdx.x] = lds[0];
}

// scan phase 2: exclusive scan of partials (tiny, one block)
__global__ void scan2_kernel(int* __restrict__ partials) {
    __shared__ int lds[128];
    int t = threadIdx.x;
    int v = (t < SCAN_BLOCKS) ? partials[t] : 0;
    lds[t] = v;
    __syncthreads();
    for (int off = 1; off < 128; off <<= 1) {
        int u = (t >= off) ? lds[t - off] : 0;
        __syncthreads();
        lds[t] += u;
        __syncthreads();
    }
    if (t < SCAN_BLOCKS) partials[t] = lds[t] - v;   // exclusive
}

// scan phase 3: in-place exclusive scan of rowptr using partial offsets
__global__ __launch_bounds__(256) void scan3_kernel(int* __restrict__ rowptr,
                                                    const int* __restrict__ partials) {
    __shared__ int lds[256];
    int t = threadIdx.x;
    int base = blockIdx.x * SCAN_CHUNK + t * 4;
    int v[4];
    int sum = 0;
    #pragma unroll
    for (int k = 0; k < 4; ++k) {
        int i = base + k;
        v[k] = (i < NNODES) ? rowptr[i] : 0;
        sum += v[k];
    }
    lds[t] = sum;
    __syncthreads();
    for (int off = 1; off < 256; off <<= 1) {
        int u = (t >= off) ? lds[t - off] : 0;
        __syncthreads();
        lds[t] += u;
        __syncthreads();
    }
    int run = partials[blockIdx.x] + lds[t] - sum;   // exclusive prefix for this thread
    #pragma unroll
    for (int k = 0; k < 4; ++k) {
        int i = base + k;
        if (i < NNODES) rowptr[i] = run;
        run += v[k];
    }
}

// dst-range-partitioned scatter of {src,w} into CSR order.
// Blocks with bid%8==g handle only dst in [g*RSPAN,(g+1)*RSPAN): with default
// round-robin block->XCD mapping, each XCD's scattered stores land in a 1.6 MB
// slice of csr_sw that stays resident in its L2 -> ~1x write amplification
// (vs 8x when every 8B store dirties its own 64B line).
// rowptr[t] becomes END pointer of row t.
__global__ __launch_bounds__(256) void build_kernel(const int* __restrict__ dst,
                                                    const int* __restrict__ src,
                                                    const float* __restrict__ w,
                                                    int* __restrict__ rowptr,
                                                    int2* __restrict__ csr_sw) {
    int g   = blockIdx.x & (NRANGE - 1);
    int sub = blockIdx.x >> 3;
    int lo = g * RSPAN;
    int hi = lo + RSPAN;
    int tid = sub * blockDim.x + threadIdx.x;
    const int4* dst4 = (const int4*)dst;
    const int n4 = NEDGES / 4;
    for (int i = tid; i < n4; i += GSTRIDE) {
        int4 d4 = dst4[i];
        int e = i * 4;
        int dv[4] = {d4.x, d4.y, d4.z, d4.w};
        #pragma unroll
        for (int k = 0; k < 4; ++k) {
            int t = dv[k];
            if (t >= lo && t < hi) {
                int pos = atomicAdd(&rowptr[t], 1);
                csr_sw[pos] = make_int2(src[e + k], __float_as_int(w[e + k]));
            }
        }
    }
}

// ---------------- aggregation ----------------
// After build: row t spans [ t ? rowptr[t-1] : 0 , rowptr[t] ).

// one 64-lane wave per node; acc += sum_e x[src_e] * w_e  (8 gathers in flight)
__device__ __forceinline__ void agg_row(const float2* __restrict__ xf2,
                                        const int2* __restrict__ csr_sw,
                                        int beg, int end, int lane,
                                        float2& acc) {
    for (int base = beg; base < end; base += 64) {
        int cnt = end - base; if (cnt > 64) cnt = 64;
        int2 sw = make_int2(0, 0);
        if (lane < cnt) sw = csr_sw[base + lane];
        int   my_s = sw.x;
        float my_w = __int_as_float(sw.y);
        int d = 0;
        for (; d + 8 <= cnt; d += 8) {
            int s[8]; float wv[8]; float2 v[8];
            #pragma unroll
            for (int k = 0; k < 8; ++k) {
                s[k]  = __shfl(my_s, d + k);
                wv[k] = __shfl(my_w, d + k);
            }
            #pragma unroll
            for (int k = 0; k < 8; ++k) v[k] = xf2[(size_t)s[k] * 64 + lane];
            #pragma unroll
            for (int k = 0; k < 8; ++k) {
                acc.x += v[k].x * wv[k];
                acc.y += v[k].y * wv[k];
            }
        }
        for (; d + 4 <= cnt; d += 4) {
            int s[4]; float wv[4]; float2 v[4];
            #pragma unroll
            for (int k = 0; k < 4; ++k) {
                s[k]  = __shfl(my_s, d + k);
                wv[k] = __shfl(my_w, d + k);
            }
            #pragma unroll
            for (int k = 0; k < 4; ++k) v[k] = xf2[(size_t)s[k] * 64 + lane];
            #pragma unroll
            for (int k = 0; k < 4; ++k) {
                acc.x += v[k].x * wv[k];
                acc.y += v[k].y * wv[k];
            }
        }
        for (; d < cnt; ++d) {
            int   s = __shfl(my_s, d);
            float wv = __shfl(my_w, d);
            float2 v = xf2[(size_t)s * 64 + lane];
            acc.x += v.x * wv; acc.y += v.y * wv;
        }
    }
}

__global__ __launch_bounds__(256) void agg1_kernel(const float* __restrict__ x,
                                                   const int2* __restrict__ csr_sw,
                                                   const int* __restrict__ rowptr,
                                                   float* __restrict__ x1) {
    int gid = blockIdx.x * blockDim.x + threadIdx.x;
    int node = gid >> 6;
    if (node >= NNODES) return;
    int lane = threadIdx.x & 63;
    int beg = node ? rowptr[node - 1] : 0;
    int end = rowptr[node];
    const float2* xf2 = (const float2*)x;
    float2 acc = xf2[(size_t)node * 64 + lane];  // residual (overlaps segment load)
    agg_row(xf2, csr_sw, beg, end, lane, acc);
    ((float2*)x1)[(size_t)node * 64 + lane] = acc;
}

__global__ __launch_bounds__(256) void agg2_kernel(const float* __restrict__ x1,
                                                   const int2* __restrict__ csr_sw,
                                                   const int* __restrict__ rowptr,
                                                   const int* __restrict__ sel,
                                                   float* __restrict__ out) {
    int gid = blockIdx.x * blockDim.x + threadIdx.x;
    int row = gid >> 6;
    if (row >= NPOOL) return;
    int lane = threadIdx.x & 63;
    int node = sel[row];
    int beg = node ? rowptr[node - 1] : 0;
    int end = rowptr[node];
    const float2* xf2 = (const float2*)x1;
    float2 acc = xf2[(size_t)node * 64 + lane];  // residual
    agg_row(xf2, csr_sw, beg, end, lane, acc);
    ((float2*)out)[(size_t)row * 64 + lane] = acc;
}

// ---------------- launch ----------------

extern "C" void kernel_launch(void* const* d_in, const int* in_sizes, int n_in,
                              void* d_out, int out_size, void* d_ws, size_t ws_size,
                              hipStream_t stream) {
    const float* x         = (const float*)d_in[0];            // [NNODES, DFEAT]
    const float* edge_attr = (const float*)d_in[1];            // [NEDGES]
    const int*   edge_idx  = (const int*)d_in[2];              // [2, NEDGES]
    const int*   sel       = (const int*)d_in[3];              // [NPOOL]
    const int*   src = edge_idx;
    const int*   dst = edge_idx + NEDGES;
    float* out = (float*)d_out;

    // workspace layout: 51.2 + 0.4 + 12.8 + tiny = ~64.4 MB
    char* ws = (char*)d_ws;
    float* x1       = (float*)ws;  ws += (size_t)NNODES * DFEAT * sizeof(float);  // 51.2 MB
    int*   rowptr   = (int*)ws;    ws += (size_t)NNODES * sizeof(int);            // 0.4 MB
    int2*  csr_sw   = (int2*)ws;   ws += (size_t)NEDGES * sizeof(int2);           // 12.8 MB
    int*   partials = (int*)ws;    ws += (size_t)SCAN_BLOCKS * sizeof(int);

    // rowptr = 0 (histogram -> scan in-place -> end-pointers after build)
    hipMemsetAsync(rowptr, 0, (size_t)NNODES * sizeof(int), stream);

    // 1) histogram of dst
    hist_kernel<<<(NEDGES / 4 + 255) / 256, 256, 0, stream>>>(dst, rowptr);
    // 2) hierarchical exclusive scan (in-place on rowptr)
    scan1_kernel<<<SCAN_BLOCKS, 256, 0, stream>>>(rowptr, partials);
    scan2_kernel<<<1, 128, 0, stream>>>(partials);
    scan3_kernel<<<SCAN_BLOCKS, 256, 0, stream>>>(rowptr, partials);
    // 3) dst-range-partitioned bucket scatter {src,w}; rowptr becomes end-pointers
    build_kernel<<<BUILD_BLOCKS, 256, 0, stream>>>(dst, src, edge_attr, rowptr, csr_sw);

    // 4) hop 1 (all nodes)
    {
        long long threads = (long long)NNODES * 64;
        int blocks = (int)((threads + 255) / 256);
        agg1_kernel<<<blocks, 256, 0, stream>>>(x, csr_sw, rowptr, x1);
    }
    // 5) hop 2 (selected rows only), fused with residual + output gather
    {
        long long threads = (long long)NPOOL * 64;
        int blocks = (int)((threads + 255) / 256);
        agg2_kernel<<<blocks, 256, 0, stream>>>(x1, csr_sw, rowptr, sel, out);
    }
}

// Round 6
// 245.881 us; speedup vs baseline: 13.4647x; 1.2371x over previous
//
#include <hip/hip_runtime.h>

#define NNODES 100000
#define NEDGES 1600000
#define DFEAT  128
#define NPOOL  25000

#define SCAN_CHUNK 1024                              // elements per scan block
#define SCAN_BLOCKS ((NNODES + SCAN_CHUNK - 1) / SCAN_CHUNK)   // 98

#define NRANGE 8                                     // dst-range groups (== XCDs)
#define RSPAN ((NNODES + NRANGE - 1) / NRANGE)       // 12500 nodes per range
#define BUILD_BLOCKS 2048
#define GSTRIDE ((BUILD_BLOCKS / NRANGE) * 256)      // threads per range group

// bf16 RNE helpers (manual, deterministic)
__device__ __forceinline__ unsigned int f2bf(float f) {
    unsigned int b = __float_as_uint(f);
    return (b + 0x7fffu + ((b >> 16) & 1u)) >> 16;
}
__device__ __forceinline__ float bf2f_lo(unsigned int packed) {
    return __uint_as_float(packed << 16);
}
__device__ __forceinline__ float bf2f_hi(unsigned int packed) {
    return __uint_as_float(packed & 0xffff0000u);
}

// ---------------- convert x (f32) -> xh (bf16) ----------------
// linear: xh[i] = bf16(x[i]); 8 elems/thread
__global__ __launch_bounds__(256) void convert_kernel(const float* __restrict__ x,
                                                      unsigned int* __restrict__ xh_u32) {
    int i = blockIdx.x * blockDim.x + threadIdx.x;   // over (NNODES*DFEAT)/8
    const int n8 = NNODES * DFEAT / 8;
    if (i >= n8) return;
    float4 a = ((const float4*)x)[i * 2 + 0];
    float4 b = ((const float4*)x)[i * 2 + 1];
    uint4 o;
    o.x = f2bf(a.x) | (f2bf(a.y) << 16);
    o.y = f2bf(a.z) | (f2bf(a.w) << 16);
    o.z = f2bf(b.x) | (f2bf(b.y) << 16);
    o.w = f2bf(b.z) | (f2bf(b.w) << 16);
    ((uint4*)xh_u32)[i] = o;
}

// ---------------- CSR build ----------------

// histogram of dst into rowptr (pre-zeroed), 4 edges/thread for MLP
__global__ __launch_bounds__(256) void hist_kernel(const int* __restrict__ dst,
                                                   int* __restrict__ rowptr) {
    int i = blockIdx.x * blockDim.x + threadIdx.x;   // over NEDGES/4 int4s
    const int n4 = NEDGES / 4;
    if (i >= n4) return;
    int4 d4 = ((const int4*)dst)[i];
    atomicAdd(&rowptr[d4.x], 1);
    atomicAdd(&rowptr[d4.y], 1);
    atomicAdd(&rowptr[d4.z], 1);
    atomicAdd(&rowptr[d4.w], 1);
}

// scan phase 1: per-block sums of rowptr -> partials
__global__ __launch_bounds__(256) void scan1_kernel(const int* __restrict__ rowptr,
                                                    int* __restrict__ partials) {
    __shared__ int lds[256];
    int t = threadIdx.x;
    int base = blockIdx.x * SCAN_CHUNK + t * 4;
    int sum = 0;
    #pragma unroll
    for (int k = 0; k < 4; ++k) {
        int i = base + k;
        if (i < NNODES) sum += rowptr[i];
    }
    lds[t] = sum;
    __syncthreads();
    for (int off = 128; off > 0; off >>= 1) {
        if (t < off) lds[t] += lds[t + off];
        __syncthreads();
    }
    if (t == 0) partials[blockIdx.x] = lds[0];
}

// scan phase 2: exclusive scan of partials (tiny, one block)
__global__ void scan2_kernel(int* __restrict__ partials) {
    __shared__ int lds[128];
    int t = threadIdx.x;
    int v = (t < SCAN_BLOCKS) ? partials[t] : 0;
    lds[t] = v;
    __syncthreads();
    for (int off = 1; off < 128; off <<= 1) {
        int u = (t >= off) ? lds[t - off] : 0;
        __syncthreads();
        lds[t] += u;
        __syncthreads();
    }
    if (t < SCAN_BLOCKS) partials[t] = lds[t] - v;   // exclusive
}

// scan phase 3: in-place exclusive scan of rowptr using partial offsets
__global__ __launch_bounds__(256) void scan3_kernel(int* __restrict__ rowptr,
                                                    const int* __restrict__ partials) {
    __shared__ int lds[256];
    int t = threadIdx.x;
    int base = blockIdx.x * SCAN_CHUNK + t * 4;
    int v[4];
    int sum = 0;
    #pragma unroll
    for (int k = 0; k < 4; ++k) {
        int i = base + k;
        v[k] = (i < NNODES) ? rowptr[i] : 0;
        sum += v[k];
    }
    lds[t] = sum;
    __syncthreads();
    for (int off = 1; off < 256; off <<= 1) {
        int u = (t >= off) ? lds[t - off] : 0;
        __syncthreads();
        lds[t] += u;
        __syncthreads();
    }
    int run = partials[blockIdx.x] + lds[t] - sum;   // exclusive prefix for this thread
    #pragma unroll
    for (int k = 0; k < 4; ++k) {
        int i = base + k;
        if (i < NNODES) rowptr[i] = run;
        run += v[k];
    }
}

// dst-range-partitioned scatter of {src,w} into CSR order (XCD write locality).
// rowptr[t] becomes END pointer of row t.
__global__ __launch_bounds__(256) void build_kernel(const int* __restrict__ dst,
                                                    const int* __restrict__ src,
                                                    const float* __restrict__ w,
                                                    int* __restrict__ rowptr,
                                                    int2* __restrict__ csr_sw) {
    int g   = blockIdx.x & (NRANGE - 1);
    int sub = blockIdx.x >> 3;
    int lo = g * RSPAN;
    int hi = lo + RSPAN;
    int tid = sub * blockDim.x + threadIdx.x;
    const int4* dst4 = (const int4*)dst;
    const int n4 = NEDGES / 4;
    for (int i = tid; i < n4; i += GSTRIDE) {
        int4 d4 = dst4[i];
        int e = i * 4;
        int dv[4] = {d4.x, d4.y, d4.z, d4.w};
        #pragma unroll
        for (int k = 0; k < 4; ++k) {
            int t = dv[k];
            if (t >= lo && t < hi) {
                int pos = atomicAdd(&rowptr[t], 1);
                csr_sw[pos] = make_int2(src[e + k], __float_as_int(w[e + k]));
            }
        }
    }
}

// ---------------- aggregation ----------------
// After build: row t spans [ t ? rowptr[t-1] : 0 , rowptr[t] ).
// Gather source is bf16-packed: row = 64 uints, lane's uint = elems {2*lane, 2*lane+1}.

__device__ __forceinline__ void agg_row_bf16(const unsigned int* __restrict__ xh,
                                             const int2* __restrict__ csr_sw,
                                             int beg, int end, int lane,
                                             float2& acc) {
    for (int base = beg; base < end; base += 64) {
        int cnt = end - base; if (cnt > 64) cnt = 64;
        int2 sw = make_int2(0, 0);
        if (lane < cnt) sw = csr_sw[base + lane];
        int   my_s = sw.x;
        float my_w = __int_as_float(sw.y);
        int d = 0;
        for (; d + 8 <= cnt; d += 8) {
            int s[8]; float wv[8]; unsigned int v[8];
            #pragma unroll
            for (int k = 0; k < 8; ++k) {
                s[k]  = __shfl(my_s, d + k);
                wv[k] = __shfl(my_w, d + k);
            }
            #pragma unroll
            for (int k = 0; k < 8; ++k) v[k] = xh[(size_t)s[k] * 64 + lane];
            #pragma unroll
            for (int k = 0; k < 8; ++k) {
                acc.x += bf2f_lo(v[k]) * wv[k];
                acc.y += bf2f_hi(v[k]) * wv[k];
            }
        }
        for (; d + 4 <= cnt; d += 4) {
            int s[4]; float wv[4]; unsigned int v[4];
            #pragma unroll
            for (int k = 0; k < 4; ++k) {
                s[k]  = __shfl(my_s, d + k);
                wv[k] = __shfl(my_w, d + k);
            }
            #pragma unroll
            for (int k = 0; k < 4; ++k) v[k] = xh[(size_t)s[k] * 64 + lane];
            #pragma unroll
            for (int k = 0; k < 4; ++k) {
                acc.x += bf2f_lo(v[k]) * wv[k];
                acc.y += bf2f_hi(v[k]) * wv[k];
            }
        }
        for (; d < cnt; ++d) {
            int   s = __shfl(my_s, d);
            float wv = __shfl(my_w, d);
            unsigned int v = xh[(size_t)s * 64 + lane];
            acc.x += bf2f_lo(v) * wv;
            acc.y += bf2f_hi(v) * wv;
        }
    }
}

// hop 1: x1h[n] = bf16( xh[n] + sum_e xh[src_e] * w_e )
__global__ __launch_bounds__(256) void agg1_kernel(const unsigned int* __restrict__ xh,
                                                   const int2* __restrict__ csr_sw,
                                                   const int* __restrict__ rowptr,
                                                   unsigned int* __restrict__ x1h) {
    int gid = blockIdx.x * blockDim.x + threadIdx.x;
    int node = gid >> 6;
    if (node >= NNODES) return;
    int lane = threadIdx.x & 63;
    int beg = node ? rowptr[node - 1] : 0;
    int end = rowptr[node];
    unsigned int r = xh[(size_t)node * 64 + lane];   // residual
    float2 acc = make_float2(bf2f_lo(r), bf2f_hi(r));
    agg_row_bf16(xh, csr_sw, beg, end, lane, acc);
    x1h[(size_t)node * 64 + lane] = f2bf(acc.x) | (f2bf(acc.y) << 16);
}

// hop 2: out[row] = x1h[sel] + sum_e x1h[src_e] * w_e   (f32 output)
__global__ __launch_bounds__(256) void agg2_kernel(const unsigned int* __restrict__ x1h,
                                                   const int2* __restrict__ csr_sw,
                                                   const int* __restrict__ rowptr,
                                                   const int* __restrict__ sel,
                                                   float* __restrict__ out) {
    int gid = blockIdx.x * blockDim.x + threadIdx.x;
    int row = gid >> 6;
    if (row >= NPOOL) return;
    int lane = threadIdx.x & 63;
    int node = sel[row];
    int beg = node ? rowptr[node - 1] : 0;
    int end = rowptr[node];
    unsigned int r = x1h[(size_t)node * 64 + lane];  // residual
    float2 acc = make_float2(bf2f_lo(r), bf2f_hi(r));
    agg_row_bf16(x1h, csr_sw, beg, end, lane, acc);
    ((float2*)out)[(size_t)row * 64 + lane] = acc;
}

// ---------------- launch ----------------

extern "C" void kernel_launch(void* const* d_in, const int* in_sizes, int n_in,
                              void* d_out, int out_size, void* d_ws, size_t ws_size,
                              hipStream_t stream) {
    const float* x         = (const float*)d_in[0];            // [NNODES, DFEAT]
    const float* edge_attr = (const float*)d_in[1];            // [NEDGES]
    const int*   edge_idx  = (const int*)d_in[2];              // [2, NEDGES]
    const int*   sel       = (const int*)d_in[3];              // [NPOOL]
    const int*   src = edge_idx;
    const int*   dst = edge_idx + NEDGES;
    float* out = (float*)d_out;

    // workspace layout: 25.6 + 25.6 + 0.4 + 12.8 + tiny = 64.4 MB (proven budget)
    char* ws = (char*)d_ws;
    unsigned int* xh  = (unsigned int*)ws;  ws += (size_t)NNODES * 64 * sizeof(unsigned int); // 25.6 MB
    unsigned int* x1h = (unsigned int*)ws;  ws += (size_t)NNODES * 64 * sizeof(unsigned int); // 25.6 MB
    int*   rowptr   = (int*)ws;    ws += (size_t)NNODES * sizeof(int);            // 0.4 MB
    int2*  csr_sw   = (int2*)ws;   ws += (size_t)NEDGES * sizeof(int2);           // 12.8 MB
    int*   partials = (int*)ws;    ws += (size_t)SCAN_BLOCKS * sizeof(int);

    // rowptr = 0 (histogram -> scan in-place -> end-pointers after build)
    hipMemsetAsync(rowptr, 0, (size_t)NNODES * sizeof(int), stream);

    // 0) x -> bf16
    convert_kernel<<<(NNODES * DFEAT / 8 + 255) / 256, 256, 0, stream>>>(x, xh);
    // 1) histogram of dst
    hist_kernel<<<(NEDGES / 4 + 255) / 256, 256, 0, stream>>>(dst, rowptr);
    // 2) hierarchical exclusive scan (in-place on rowptr)
    scan1_kernel<<<SCAN_BLOCKS, 256, 0, stream>>>(rowptr, partials);
    scan2_kernel<<<1, 128, 0, stream>>>(partials);
    scan3_kernel<<<SCAN_BLOCKS, 256, 0, stream>>>(rowptr, partials);
    // 3) dst-range-partitioned bucket scatter {src,w}; rowptr becomes end-pointers
    build_kernel<<<BUILD_BLOCKS, 256, 0, stream>>>(dst, src, edge_attr, rowptr, csr_sw);

    // 4) hop 1 (all nodes), bf16 gather, bf16 store
    {
        long long threads = (long long)NNODES * 64;
        int blocks = (int)((threads + 255) / 256);
        agg1_kernel<<<blocks, 256, 0, stream>>>(xh, csr_sw, rowptr, x1h);
    }
    // 5) hop 2 (selected rows only), bf16 gather, f32 out
    {
        long long threads = (long long)NPOOL * 64;
        int blocks = (int)((threads + 255) / 256);
        agg2_kernel<<<blocks, 256, 0, stream>>>(x1h, csr_sw, rowptr, sel, out);
    }
}